// Round 2
// baseline (178.175 us; speedup 1.0000x reference)
//
#include <hip/hip_runtime.h>

#define B_      2048
#define SYN     128
#define SEM     256
#define IN_DIM  647
#define K1      704      // 647 padded to 11*64
#define HIDDEN  1024
#define OUT_N   10000
#define NNZ     8
#define NB2     40       // N-blocks of 256 for gemm2 (covers 10240, cols>=10000 guarded)

typedef __bf16 bf16x8 __attribute__((ext_vector_type(8)));
typedef float  f32x4  __attribute__((ext_vector_type(4)));

__device__ __forceinline__ unsigned short f2b(float v) {
    __bf16 b = (__bf16)v;
    return __builtin_bit_cast(unsigned short, b);
}

// ---------------------------------------------------------------- build x ---
__global__ __launch_bounds__(256) void build_x(
    const float* __restrict__ d_onehot,
    const int*   __restrict__ cat_ix,
    const int*   __restrict__ hvb_ix,
    const int*   __restrict__ hvf_ix,
    const float* __restrict__ hvb_top,
    const float* __restrict__ hvf_top,
    const float* __restrict__ cat_embeds,
    const float* __restrict__ hvec_embeds,
    unsigned short* __restrict__ xb)
{
    const int b = blockIdx.x, t = threadIdx.x;
    unsigned short* xrow = xb + (size_t)b * K1;

    if (t < SYN) {
        int c = cat_ix[b];
        xrow[t] = f2b(cat_embeds[(size_t)c * SYN + t]);
    }
    {
        int ix[NNZ];
        #pragma unroll
        for (int j = 0; j < NNZ; ++j) ix[j] = hvb_ix[b * NNZ + j];
        float s = hvb_top[(size_t)b * SEM + t];
        #pragma unroll
        for (int j = 0; j < NNZ; ++j) {
            bool dup = false;
            for (int k2 = 0; k2 < j; ++k2) dup = dup || (ix[j] == ix[k2]);
            if (!dup) s += hvec_embeds[(size_t)ix[j] * SEM + t];
        }
        xrow[SYN + t] = f2b(s);
    }
    {
        int ix[NNZ];
        #pragma unroll
        for (int j = 0; j < NNZ; ++j) ix[j] = hvf_ix[b * NNZ + j];
        float s = hvf_top[(size_t)b * SEM + t];
        #pragma unroll
        for (int j = 0; j < NNZ; ++j) {
            bool dup = false;
            for (int k2 = 0; k2 < j; ++k2) dup = dup || (ix[j] == ix[k2]);
            if (!dup) s += hvec_embeds[(size_t)ix[j] * SEM + t];
        }
        xrow[SYN + SEM + t] = f2b(s);
    }
    if (t < 7)       xrow[640 + t] = f2b(d_onehot[b * 7 + t]);
    else if (t < 64) xrow[640 + t] = 0;
}

// ------------------------------------------------------------ weight casts ---
__global__ void cvt_w1(const float* __restrict__ W1, unsigned short* __restrict__ W1b) {
    int idx = blockIdx.x * 256 + threadIdx.x;
    if (idx >= HIDDEN * K1) return;
    int r = idx / K1, c = idx - r * K1;
    W1b[idx] = f2b(c < IN_DIM ? W1[r * IN_DIM + c] : 0.f);
}

__global__ void cvt_w2(const float* __restrict__ W2, unsigned short* __restrict__ W2b) {
    size_t idx = (size_t)blockIdx.x * 256 + threadIdx.x;
    if (idx < (size_t)OUT_N * HIDDEN) W2b[idx] = f2b(W2[idx]);
}

// ---------------------------------------------------- GEMM1 (m97 128x128) ---
__global__ __launch_bounds__(256) void gemm1(
    const unsigned short* __restrict__ A,
    const unsigned short* __restrict__ Bm,
    const float* __restrict__ bias,
    unsigned short* __restrict__ H,
    int K, int N)
{
    __shared__ __align__(16) unsigned short lds_a[128 * 64];
    __shared__ __align__(16) unsigned short lds_b[128 * 64];
    const int tid = threadIdx.x;
    const int wv = tid >> 6, ln = tid & 63;
    const int wr = wv >> 1, wc = wv & 1;
    const int m0 = blockIdx.x * 128, n0 = blockIdx.y * 128;
    const int lr = ln & 15, lh = ln >> 4;

    f32x4 acc[4][4];
    {
        f32x4 z = {0.f, 0.f, 0.f, 0.f};
        #pragma unroll
        for (int i = 0; i < 4; ++i)
            #pragma unroll
            for (int j = 0; j < 4; ++j) acc[i][j] = z;
    }

    for (int kt = 0; kt < K; kt += 64) {
        #pragma unroll
        for (int i = 0; i < 4; ++i) {
            int c   = i * 256 + tid;
            int row = c >> 3, cc = c & 7;
            const unsigned short* ga = A  + (size_t)(m0 + row) * K + kt + cc * 8;
            const unsigned short* gb = Bm + (size_t)(n0 + row) * K + kt + cc * 8;
            unsigned short* la = &lds_a[(size_t)(i * 256 + wv * 64) * 8];
            unsigned short* lb = &lds_b[(size_t)(i * 256 + wv * 64) * 8];
            __builtin_amdgcn_global_load_lds((__attribute__((address_space(1))) void*)ga,
                                             (__attribute__((address_space(3))) void*)la, 16, 0, 0);
            __builtin_amdgcn_global_load_lds((__attribute__((address_space(1))) void*)gb,
                                             (__attribute__((address_space(3))) void*)lb, 16, 0, 0);
        }
        __syncthreads();

        #pragma unroll
        for (int ks = 0; ks < 2; ++ks) {
            bf16x8 af[4], bfr[4];
            #pragma unroll
            for (int mi = 0; mi < 4; ++mi)
                af[mi] = *(const bf16x8*)&lds_a[(wr * 64 + mi * 16 + lr) * 64 + ks * 32 + lh * 8];
            #pragma unroll
            for (int ni = 0; ni < 4; ++ni)
                bfr[ni] = *(const bf16x8*)&lds_b[(wc * 64 + ni * 16 + lr) * 64 + ks * 32 + lh * 8];
            #pragma unroll
            for (int mi = 0; mi < 4; ++mi)
                #pragma unroll
                for (int ni = 0; ni < 4; ++ni)
                    acc[mi][ni] = __builtin_amdgcn_mfma_f32_16x16x32_bf16(af[mi], bfr[ni], acc[mi][ni], 0, 0, 0);
        }
        __syncthreads();
    }

    #pragma unroll
    for (int mi = 0; mi < 4; ++mi)
        #pragma unroll
        for (int ni = 0; ni < 4; ++ni) {
            int col = n0 + wc * 64 + ni * 16 + lr;
            float bb = bias[col];
            #pragma unroll
            for (int r = 0; r < 4; ++r) {
                int row = m0 + wr * 64 + mi * 16 + lh * 4 + r;
                float v = acc[mi][ni][r] + bb;
                H[(size_t)row * N + col] = f2b(fmaxf(v, 0.f));
            }
        }
}

// ------------------------------------- GEMM2: 256x256, 8-wave, BK=32, 4-buf ---
// Phase-interleaved, counted vmcnt(4), LDS XOR swizzle (col bits 4-5 ^= row
// bits 1-2), staging pre-swizzles the GLOBAL source (linear LDS dest).
__global__ __launch_bounds__(512, 2) void gemm2_8ph(
    const unsigned short* __restrict__ A,    // hB: 2048 x 1024
    const unsigned short* __restrict__ Bm,   // W2b: 10000 x 1024
    const float* __restrict__ bias,
    float* __restrict__ O)                   // 2048 x 10000
{
    __shared__ unsigned short lds_a[4][256 * 32];
    __shared__ unsigned short lds_b[4][256 * 32];
    const int tid = threadIdx.x;
    const int wv = tid >> 6, ln = tid & 63;
    const int wr = wv >> 2, wc = wv & 3;       // 2M x 4N waves
    const int lr = ln & 15, lh = ln >> 4;

    // XCD-bijective swizzle: 320 blocks, 8 XCDs -> 40 each; one M-panel per XCD
    const int bid = blockIdx.x;
    const int nw  = (bid & 7) * NB2 + (bid >> 3);
    const int m0  = (nw / NB2) * 256;
    const int n0  = (nw % NB2) * 256;

    // ---- staging precompute: chunk c -> phys P=c*16B; logical col slot ^= row bits 1-2
    const int c0 = tid, c1 = tid + 512;
    const int rA0 = c0 >> 2, rA1 = c1 >> 2;                      // 0..255
    const int colL0 = (((c0 & 3) ^ ((c0 >> 3) & 3)) << 3);       // elems
    const int colL1 = (((c1 & 3) ^ ((c1 >> 3) & 3)) << 3);
    const unsigned short* sA0 = A + (size_t)(m0 + rA0) * HIDDEN + colL0;
    const unsigned short* sA1 = A + (size_t)(m0 + rA1) * HIDDEN + colL1;
    int rB0g = n0 + rA0; if (rB0g > OUT_N - 1) rB0g = OUT_N - 1;  // clamp: garbage cols guarded
    int rB1g = n0 + rA1; if (rB1g > OUT_N - 1) rB1g = OUT_N - 1;
    const unsigned short* sB0 = Bm + (size_t)rB0g * HIDDEN + colL0;
    const unsigned short* sB1 = Bm + (size_t)rB1g * HIDDEN + colL1;

    auto stageA = [&](int buf, int kt) {
        __builtin_amdgcn_global_load_lds((__attribute__((address_space(1))) void*)(sA0 + kt),
            (__attribute__((address_space(3))) void*)&lds_a[buf][c0 * 8], 16, 0, 0);
        __builtin_amdgcn_global_load_lds((__attribute__((address_space(1))) void*)(sA1 + kt),
            (__attribute__((address_space(3))) void*)&lds_a[buf][c1 * 8], 16, 0, 0);
    };
    auto stageB = [&](int buf, int kt) {
        __builtin_amdgcn_global_load_lds((__attribute__((address_space(1))) void*)(sB0 + kt),
            (__attribute__((address_space(3))) void*)&lds_b[buf][c0 * 8], 16, 0, 0);
        __builtin_amdgcn_global_load_lds((__attribute__((address_space(1))) void*)(sB1 + kt),
            (__attribute__((address_space(3))) void*)&lds_b[buf][c1 * 8], 16, 0, 0);
    };

    // ---- ds_read offsets (ushort idx): L = row*64B + lh*16B; P = L ^ ((row>>1&3)<<4)
    int a_off[8], b_off[4];
    #pragma unroll
    for (int mi = 0; mi < 8; ++mi) {
        int row = wr * 128 + mi * 16 + lr;
        int L = row * 64 + lh * 16;
        a_off[mi] = (L ^ (((row >> 1) & 3) << 4)) >> 1;
    }
    #pragma unroll
    for (int ni = 0; ni < 4; ++ni) {
        int row = wc * 64 + ni * 16 + lr;
        int L = row * 64 + lh * 16;
        b_off[ni] = (L ^ (((row >> 1) & 3) << 4)) >> 1;
    }

    f32x4 acc[8][4];
    {
        f32x4 z = {0.f, 0.f, 0.f, 0.f};
        #pragma unroll
        for (int i = 0; i < 8; ++i)
            #pragma unroll
            for (int j = 0; j < 4; ++j) acc[i][j] = z;
    }

    const int nt = HIDDEN / 32;   // 32 K-tiles
    // prologue: tiles 0,1
    stageA(0, 0);  stageB(0, 0);
    stageA(1, 32); stageB(1, 32);
    asm volatile("s_waitcnt vmcnt(4)" ::: "memory");
    __builtin_amdgcn_s_barrier();

    for (int t = 0; t < nt; ++t) {
        const int cur = t & 3;
        const int pre = (t + 2) & 3;
        int tp = t + 2; if (tp > nt - 1) tp = nt - 1;   // clamp: redundant re-stage, unread
        const int ktp = tp * 32;
        const unsigned short* la = lds_a[cur];
        const unsigned short* lb = lds_b[cur];
        bf16x8 bfv[4], afv[4];

        // ---- phase 0: bf(4) + af lo(4) reads, stage A(t+2), MFMA mi 0-3
        #pragma unroll
        for (int ni = 0; ni < 4; ++ni) bfv[ni] = *(const bf16x8*)&lb[b_off[ni]];
        #pragma unroll
        for (int mi = 0; mi < 4; ++mi) afv[mi] = *(const bf16x8*)&la[a_off[mi]];
        stageA(pre, ktp);
        __builtin_amdgcn_s_barrier();
        asm volatile("s_waitcnt lgkmcnt(0)" ::: "memory");
        __builtin_amdgcn_sched_barrier(0);
        __builtin_amdgcn_s_setprio(1);
        #pragma unroll
        for (int mi = 0; mi < 4; ++mi)
            #pragma unroll
            for (int ni = 0; ni < 4; ++ni)
                acc[mi][ni] = __builtin_amdgcn_mfma_f32_16x16x32_bf16(afv[mi], bfv[ni], acc[mi][ni], 0, 0, 0);
        __builtin_amdgcn_s_setprio(0);
        __builtin_amdgcn_s_barrier();

        // ---- phase 1: af hi(4) reads, stage B(t+2), vmcnt(4) covers tile t+1, MFMA mi 4-7
        #pragma unroll
        for (int mi = 0; mi < 4; ++mi) afv[mi] = *(const bf16x8*)&la[a_off[4 + mi]];
        stageB(pre, ktp);
        asm volatile("s_waitcnt vmcnt(4)" ::: "memory");
        __builtin_amdgcn_s_barrier();
        asm volatile("s_waitcnt lgkmcnt(0)" ::: "memory");
        __builtin_amdgcn_sched_barrier(0);
        __builtin_amdgcn_s_setprio(1);
        #pragma unroll
        for (int mi = 0; mi < 4; ++mi)
            #pragma unroll
            for (int ni = 0; ni < 4; ++ni)
                acc[4 + mi][ni] = __builtin_amdgcn_mfma_f32_16x16x32_bf16(afv[mi], bfv[ni], acc[4 + mi][ni], 0, 0, 0);
        __builtin_amdgcn_s_setprio(0);
        __builtin_amdgcn_s_barrier();
    }

    // ---- epilogue: bias + fp32 store, col-guarded
    #pragma unroll
    for (int mi = 0; mi < 8; ++mi) {
        int row = m0 + wr * 128 + mi * 16 + lh * 4;
        #pragma unroll
        for (int ni = 0; ni < 4; ++ni) {
            int col = n0 + wc * 64 + ni * 16 + lr;
            if (col < OUT_N) {
                float bb = bias[col];
                #pragma unroll
                for (int r = 0; r < 4; ++r)
                    O[(size_t)(row + r) * OUT_N + col] = acc[mi][ni][r] + bb;
            }
        }
    }
}

// ------------------------------------------------------- in-place logsoftmax ---
__global__ __launch_bounds__(256) void lsm(float* __restrict__ out) {
    __shared__ __align__(16) float rowbuf[OUT_N];
    __shared__ float red[8];
    const int t = threadIdx.x, wv = t >> 6, ln = t & 63;
    float* o = out + (size_t)blockIdx.x * OUT_N;

    float mx = -3.4e38f;
    for (int i = t; i < OUT_N; i += 256) {
        float v = o[i];
        rowbuf[i] = v;
        mx = fmaxf(mx, v);
    }
    #pragma unroll
    for (int off = 32; off > 0; off >>= 1) mx = fmaxf(mx, __shfl_xor(mx, off, 64));
    if (ln == 0) red[wv] = mx;
    __syncthreads();
    float m4 = fmaxf(fmaxf(red[0], red[1]), fmaxf(red[2], red[3]));

    float s = 0.f;
    for (int i = t; i < OUT_N; i += 256) s += __expf(rowbuf[i] - m4);
    #pragma unroll
    for (int off = 32; off > 0; off >>= 1) s += __shfl_xor(s, off, 64);
    if (ln == 0) red[4 + wv] = s;
    __syncthreads();
    float lz = m4 + logf(red[4] + red[5] + red[6] + red[7]);

    for (int i = t; i < OUT_N; i += 256) o[i] = rowbuf[i] - lz;
}

// ----------------------------------------------------------------- launch ---
extern "C" void kernel_launch(void* const* d_in, const int* in_sizes, int n_in,
                              void* d_out, int out_size, void* d_ws, size_t ws_size,
                              hipStream_t stream) {
    const float* d_onehot    = (const float*)d_in[0];
    const int*   cat_ix      = (const int*)  d_in[1];
    const int*   hvb_ix      = (const int*)  d_in[2];
    const int*   hvf_ix      = (const int*)  d_in[3];
    const float* hvb_top     = (const float*)d_in[4];
    const float* hvf_top     = (const float*)d_in[5];
    const float* cat_embeds  = (const float*)d_in[6];
    const float* hvec_embeds = (const float*)d_in[7];
    const float* W1          = (const float*)d_in[8];
    const float* b1          = (const float*)d_in[9];
    const float* W2          = (const float*)d_in[10];
    const float* b2          = (const float*)d_in[11];
    float* out = (float*)d_out;

    unsigned short* xb  = (unsigned short*)d_ws;               // 2048 x 704
    unsigned short* W1b = xb  + (size_t)B_ * K1;               // 1024 x 704
    unsigned short* hB  = W1b + (size_t)HIDDEN * K1;           // 2048 x 1024
    unsigned short* W2b = hB  + (size_t)B_ * HIDDEN;           // 10000 x 1024

    cvt_w1<<<dim3((HIDDEN * K1 + 255) / 256), dim3(256), 0, stream>>>(W1, W1b);
    cvt_w2<<<dim3((OUT_N * HIDDEN) / 256), dim3(256), 0, stream>>>(W2, W2b);
    build_x<<<dim3(B_), dim3(256), 0, stream>>>(d_onehot, cat_ix, hvb_ix, hvf_ix,
                                                hvb_top, hvf_top, cat_embeds, hvec_embeds, xb);
    gemm1<<<dim3(B_ / 128, HIDDEN / 128), dim3(256), 0, stream>>>(
        xb, W1b, b1, hB, K1, HIDDEN);
    gemm2_8ph<<<dim3(8 * NB2), dim3(512), 0, stream>>>(hB, W2b, b2, out);
    lsm<<<dim3(B_), dim3(256), 0, stream>>>(out);
}

// Round 3
// 119.223 us; speedup vs baseline: 1.4945x; 1.4945x over previous
//
#include <hip/hip_runtime.h>

#define B_      2048
#define SYN     128
#define SEM     256
#define IN_DIM  647
#define K1      704      // 647 padded to 22*32
#define HIDDEN  1024
#define OUT_N   10000
#define NNZ     8

typedef __bf16 bf16x8 __attribute__((ext_vector_type(8)));
typedef float  f32x4  __attribute__((ext_vector_type(4)));
typedef __attribute__((address_space(3))) const unsigned short* lds_cp;

__device__ __forceinline__ unsigned short f2b(float v) {
    __bf16 b = (__bf16)v;
    return __builtin_bit_cast(unsigned short, b);
}
__device__ __forceinline__ float b2f(unsigned short u) {
    unsigned v = ((unsigned)u) << 16;
    return __builtin_bit_cast(float, v);
}

// ---------------------------------------------------------------- build x ---
__global__ __launch_bounds__(256) void build_x(
    const float* __restrict__ d_onehot,
    const int*   __restrict__ cat_ix,
    const int*   __restrict__ hvb_ix,
    const int*   __restrict__ hvf_ix,
    const float* __restrict__ hvb_top,
    const float* __restrict__ hvf_top,
    const float* __restrict__ cat_embeds,
    const float* __restrict__ hvec_embeds,
    unsigned short* __restrict__ xb)
{
    const int b = blockIdx.x, t = threadIdx.x;
    unsigned short* xrow = xb + (size_t)b * K1;

    if (t < SYN) {
        int c = cat_ix[b];
        xrow[t] = f2b(cat_embeds[(size_t)c * SYN + t]);
    }
    {
        int ix[NNZ];
        #pragma unroll
        for (int j = 0; j < NNZ; ++j) ix[j] = hvb_ix[b * NNZ + j];
        float s = hvb_top[(size_t)b * SEM + t];
        #pragma unroll
        for (int j = 0; j < NNZ; ++j) {
            bool dup = false;
            for (int k2 = 0; k2 < j; ++k2) dup = dup || (ix[j] == ix[k2]);
            if (!dup) s += hvec_embeds[(size_t)ix[j] * SEM + t];
        }
        xrow[SYN + t] = f2b(s);
    }
    {
        int ix[NNZ];
        #pragma unroll
        for (int j = 0; j < NNZ; ++j) ix[j] = hvf_ix[b * NNZ + j];
        float s = hvf_top[(size_t)b * SEM + t];
        #pragma unroll
        for (int j = 0; j < NNZ; ++j) {
            bool dup = false;
            for (int k2 = 0; k2 < j; ++k2) dup = dup || (ix[j] == ix[k2]);
            if (!dup) s += hvec_embeds[(size_t)ix[j] * SEM + t];
        }
        xrow[SYN + SEM + t] = f2b(s);
    }
    if (t < 7)       xrow[640 + t] = f2b(d_onehot[b * 7 + t]);
    else if (t < 64) xrow[640 + t] = 0;
}

// ------------------------------------------------------------ weight casts ---
__global__ void cvt_w1(const float* __restrict__ W1, unsigned short* __restrict__ W1b) {
    int idx = blockIdx.x * 256 + threadIdx.x;
    if (idx >= HIDDEN * K1) return;
    int r = idx / K1, c = idx - r * K1;
    W1b[idx] = f2b(c < IN_DIM ? W1[r * IN_DIM + c] : 0.f);
}

// vectorized: 2x float4 in, 1x 16B out per thread
__global__ __launch_bounds__(256) void cvt_w2(const float* __restrict__ W2,
                                              unsigned short* __restrict__ W2b) {
    size_t i = (size_t)blockIdx.x * 256 + threadIdx.x;      // 8-elem group id
    if (i >= (size_t)OUT_N * HIDDEN / 8) return;
    const float4* src = (const float4*)(W2 + i * 8);
    float4 a = src[0], b = src[1];
    ushort u[8] = { f2b(a.x), f2b(a.y), f2b(a.z), f2b(a.w),
                    f2b(b.x), f2b(b.y), f2b(b.z), f2b(b.w) };
    *(uint4*)(W2b + i * 8) = *(const uint4*)u;
}

// ------------------------------------------------------------- GEMM template ---
// C = A(M,K) @ B(N,K)^T, bf16 in, fp32 acc. BM=128, BN=32*NI, BK=32.
// 4 waves (2Mx2N), per-wave 64 x 16*NI. 4-buffer LDS ring, counted vmcnt,
// inline-asm ds_read_b128 with uniform XOR swizzle, 1 barrier/iter.
// MODE 0: bias+relu -> bf16.  MODE 1: bias -> bf16, col guard.
// MODE 2: bias -> fp32, col guard.
template<int NI, int MODE>
__global__ __launch_bounds__(256) void gemm_rt(
    const unsigned short* __restrict__ A,
    const unsigned short* __restrict__ Bm,
    const float* __restrict__ bias,
    void* __restrict__ outp,
    int K, int nt, int ncols, int nbm1, int nm)   // nt=K/32, nbm1=B rows-1
{
    constexpr int BN    = 32 * NI;
    constexpr int NB_CH = NI / 2;            // B gload chunks per thread (1 or 2)
    __shared__ __align__(16) unsigned short lds_a[4][128 * 32];
    __shared__ __align__(16) unsigned short lds_b[4][BN * 32];

    const int tid = threadIdx.x;
    const int wv = tid >> 6, ln = tid & 63;
    const int wr = wv >> 1, wc = wv & 1;
    const int lr = ln & 15, lh = ln >> 4;

    // XCD-bijective swizzle (grid % 8 == 0), n-major tile order
    const int g   = gridDim.x;
    const int nw  = (blockIdx.x & 7) * (g >> 3) + (blockIdx.x >> 3);
    const int mt  = nw % nm, ntile = nw / nm;
    const int m0  = mt * 128, n0 = ntile * BN;

    // ---- staging source precompute (pre-swizzled global source, linear LDS dest)
    // chunk c: row=c>>2, phys slot=c&3 holds logical slot (c&3)^((c>>3)&3)
    const unsigned short* srcA[2];
    const unsigned short* srcB[NB_CH];
    #pragma unroll
    for (int i = 0; i < 2; ++i) {
        int c = tid + i * 256;
        int row = c >> 2, colL = (((c & 3) ^ ((c >> 3) & 3)) << 3);
        srcA[i] = A + (size_t)(m0 + row) * K + colL;
    }
    #pragma unroll
    for (int j = 0; j < NB_CH; ++j) {
        int c = tid + j * 256;
        int row = c >> 2, colL = (((c & 3) ^ ((c >> 3) & 3)) << 3);
        int gr = n0 + row; if (gr > nbm1) gr = nbm1;
        srcB[j] = Bm + (size_t)gr * K + colL;
    }

    auto stage = [&](int buf, int kt) {
        #pragma unroll
        for (int i = 0; i < 2; ++i)
            __builtin_amdgcn_global_load_lds(
                (__attribute__((address_space(1))) const void*)(srcA[i] + kt),
                (__attribute__((address_space(3))) void*)&lds_a[buf][(tid + i * 256) * 8], 16, 0, 0);
        #pragma unroll
        for (int j = 0; j < NB_CH; ++j)
            __builtin_amdgcn_global_load_lds(
                (__attribute__((address_space(1))) const void*)(srcB[j] + kt),
                (__attribute__((address_space(3))) void*)&lds_b[buf][(tid + j * 256) * 8], 16, 0, 0);
    };

    // ---- swizzled ds_read byte offsets
    int a_off[4], b_off[NI];
    #pragma unroll
    for (int mi = 0; mi < 4; ++mi) {
        int row = wr * 64 + mi * 16 + lr;
        a_off[mi] = (row * 64 + lh * 16) ^ (((row >> 1) & 3) << 4);
    }
    #pragma unroll
    for (int ni = 0; ni < NI; ++ni) {
        int row = wc * 16 * NI + ni * 16 + lr;
        b_off[ni] = (row * 64 + lh * 16) ^ (((row >> 1) & 3) << 4);
    }

    f32x4 acc[4][NI];
    {
        f32x4 z = {0.f, 0.f, 0.f, 0.f};
        #pragma unroll
        for (int i = 0; i < 4; ++i)
            #pragma unroll
            for (int j = 0; j < NI; ++j) acc[i][j] = z;
    }

    // ---- prologue: stage tiles 0,1; wait tile 0
    stage(0, 0);
    stage(1, 32);
    if constexpr (NI == 4) asm volatile("s_waitcnt vmcnt(4)" ::: "memory");
    else                   asm volatile("s_waitcnt vmcnt(3)" ::: "memory");
    __builtin_amdgcn_s_barrier();
    asm volatile("" ::: "memory");

    for (int t = 0; t < nt; ++t) {
        const int cur = t & 3, pre = (t + 2) & 3;
        int tp = t + 2; if (tp > nt - 1) tp = nt - 1;

        // ---- fragment loads: inline-asm ds_read_b128 (no compiler auto-waits)
        bf16x8 af[4], bfv[NI];
        lds_cp pa = (lds_cp)&lds_a[cur][0];
        lds_cp pb = (lds_cp)&lds_b[cur][0];
        #pragma unroll
        for (int mi = 0; mi < 4; ++mi) {
            unsigned ad = (unsigned)(unsigned long long)pa + a_off[mi];
            asm volatile("ds_read_b128 %0, %1" : "=v"(af[mi]) : "v"(ad));
        }
        #pragma unroll
        for (int ni = 0; ni < NI; ++ni) {
            unsigned ad = (unsigned)(unsigned long long)pb + b_off[ni];
            asm volatile("ds_read_b128 %0, %1" : "=v"(bfv[ni]) : "v"(ad));
        }

        // ---- prefetch tile t+2 (counted, never drained in-loop)
        stage(pre, tp * 32);

        // ---- rule #18: manual wait for asm ds_reads, then pin
        asm volatile("s_waitcnt lgkmcnt(0)" ::: "memory");
        __builtin_amdgcn_sched_barrier(0);

        __builtin_amdgcn_s_setprio(1);
        #pragma unroll
        for (int mi = 0; mi < 4; ++mi)
            #pragma unroll
            for (int ni = 0; ni < NI; ++ni)
                acc[mi][ni] = __builtin_amdgcn_mfma_f32_16x16x32_bf16(af[mi], bfv[ni], acc[mi][ni], 0, 0, 0);
        __builtin_amdgcn_s_setprio(0);

        // ---- tile t+1 must be resident before next iter reads it
        if constexpr (NI == 4) asm volatile("s_waitcnt vmcnt(4)" ::: "memory");
        else                   asm volatile("s_waitcnt vmcnt(3)" ::: "memory");
        __builtin_amdgcn_s_barrier();
        asm volatile("" ::: "memory");
    }

    // ---- epilogue: C/D layout col=ln&15, row=(ln>>4)*4+r
    #pragma unroll
    for (int mi = 0; mi < 4; ++mi) {
        int row = m0 + wr * 64 + mi * 16 + lh * 4;
        #pragma unroll
        for (int ni = 0; ni < NI; ++ni) {
            int col = n0 + wc * 16 * NI + ni * 16 + lr;
            if (col < ncols) {
                float bb = bias[col];
                if (MODE == 0) {
                    unsigned short* H = (unsigned short*)outp;
                    #pragma unroll
                    for (int r = 0; r < 4; ++r)
                        H[(size_t)(row + r) * ncols + col] = f2b(fmaxf(acc[mi][ni][r] + bb, 0.f));
                } else if (MODE == 1) {
                    unsigned short* H = (unsigned short*)outp;
                    #pragma unroll
                    for (int r = 0; r < 4; ++r)
                        H[(size_t)(row + r) * ncols + col] = f2b(acc[mi][ni][r] + bb);
                } else {
                    float* O = (float*)outp;
                    #pragma unroll
                    for (int r = 0; r < 4; ++r)
                        O[(size_t)(row + r) * ncols + col] = acc[mi][ni][r] + bb;
                }
            }
        }
    }
}

// --------------------------------------------- logsoftmax, bf16-logit input ---
__global__ __launch_bounds__(256) void lsm_b(const unsigned short* __restrict__ lg,
                                             float* __restrict__ out) {
    __shared__ __align__(16) float rowbuf[OUT_N];
    __shared__ float red[8];
    const int t = threadIdx.x, wv = t >> 6, ln = t & 63;
    const unsigned short* l = lg + (size_t)blockIdx.x * OUT_N;
    float* o = out + (size_t)blockIdx.x * OUT_N;

    float mx = -3.4e38f;
    for (int i = t; i < OUT_N / 8; i += 256) {          // 1250 groups of 8
        uint4 v = ((const uint4*)l)[i];
        float f[8];
        unsigned w[4] = {v.x, v.y, v.z, v.w};
        #pragma unroll
        for (int j = 0; j < 4; ++j) {
            f[2*j]   = __builtin_bit_cast(float, w[j] << 16);
            f[2*j+1] = __builtin_bit_cast(float, w[j] & 0xffff0000u);
        }
        #pragma unroll
        for (int j = 0; j < 8; ++j) {
            rowbuf[i * 8 + j] = f[j];
            mx = fmaxf(mx, f[j]);
        }
    }
    #pragma unroll
    for (int off = 32; off > 0; off >>= 1) mx = fmaxf(mx, __shfl_xor(mx, off, 64));
    if (ln == 0) red[wv] = mx;
    __syncthreads();
    float m4 = fmaxf(fmaxf(red[0], red[1]), fmaxf(red[2], red[3]));

    float s = 0.f;
    for (int i = t; i < OUT_N; i += 256) s += __expf(rowbuf[i] - m4);
    #pragma unroll
    for (int off = 32; off > 0; off >>= 1) s += __shfl_xor(s, off, 64);
    if (ln == 0) red[4 + wv] = s;
    __syncthreads();
    float lz = m4 + logf(red[4] + red[5] + red[6] + red[7]);

    for (int i = t; i < OUT_N / 4; i += 256) {          // 2500 float4 stores
        float4 v = { rowbuf[i*4] - lz, rowbuf[i*4+1] - lz,
                     rowbuf[i*4+2] - lz, rowbuf[i*4+3] - lz };
        ((float4*)o)[i] = v;
    }
}

// --------------------------------------------- logsoftmax, fp32 in-place ---
__global__ __launch_bounds__(256) void lsm_f(float* __restrict__ out) {
    __shared__ __align__(16) float rowbuf[OUT_N];
    __shared__ float red[8];
    const int t = threadIdx.x, wv = t >> 6, ln = t & 63;
    float* o = out + (size_t)blockIdx.x * OUT_N;

    float mx = -3.4e38f;
    for (int i = t; i < OUT_N / 4; i += 256) {
        float4 v = ((const float4*)o)[i];
        rowbuf[i*4] = v.x; rowbuf[i*4+1] = v.y; rowbuf[i*4+2] = v.z; rowbuf[i*4+3] = v.w;
        mx = fmaxf(fmaxf(mx, fmaxf(v.x, v.y)), fmaxf(v.z, v.w));
    }
    #pragma unroll
    for (int off = 32; off > 0; off >>= 1) mx = fmaxf(mx, __shfl_xor(mx, off, 64));
    if (ln == 0) red[wv] = mx;
    __syncthreads();
    float m4 = fmaxf(fmaxf(red[0], red[1]), fmaxf(red[2], red[3]));

    float s = 0.f;
    for (int i = t; i < OUT_N; i += 256) s += __expf(rowbuf[i] - m4);
    #pragma unroll
    for (int off = 32; off > 0; off >>= 1) s += __shfl_xor(s, off, 64);
    if (ln == 0) red[4 + wv] = s;
    __syncthreads();
    float lz = m4 + logf(red[4] + red[5] + red[6] + red[7]);

    for (int i = t; i < OUT_N / 4; i += 256) {
        float4 v = { rowbuf[i*4] - lz, rowbuf[i*4+1] - lz,
                     rowbuf[i*4+2] - lz, rowbuf[i*4+3] - lz };
        ((float4*)o)[i] = v;
    }
}

// ----------------------------------------------------------------- launch ---
extern "C" void kernel_launch(void* const* d_in, const int* in_sizes, int n_in,
                              void* d_out, int out_size, void* d_ws, size_t ws_size,
                              hipStream_t stream) {
    const float* d_onehot    = (const float*)d_in[0];
    const int*   cat_ix      = (const int*)  d_in[1];
    const int*   hvb_ix      = (const int*)  d_in[2];
    const int*   hvf_ix      = (const int*)  d_in[3];
    const float* hvb_top     = (const float*)d_in[4];
    const float* hvf_top     = (const float*)d_in[5];
    const float* cat_embeds  = (const float*)d_in[6];
    const float* hvec_embeds = (const float*)d_in[7];
    const float* W1          = (const float*)d_in[8];
    const float* b1          = (const float*)d_in[9];
    const float* W2          = (const float*)d_in[10];
    const float* b2          = (const float*)d_in[11];
    float* out = (float*)d_out;

    unsigned short* xb  = (unsigned short*)d_ws;               // 2048 x 704
    unsigned short* W1b = xb  + (size_t)B_ * K1;               // 1024 x 704
    unsigned short* hB  = W1b + (size_t)HIDDEN * K1;           // 2048 x 1024
    unsigned short* W2b = hB  + (size_t)B_ * HIDDEN;           // 10000 x 1024
    unsigned short* lg  = W2b + (size_t)OUT_N * HIDDEN;        // 2048 x 10000 bf16 logits
    const size_t need = ((size_t)B_*K1 + (size_t)HIDDEN*K1 + (size_t)B_*HIDDEN
                         + (size_t)OUT_N*HIDDEN + (size_t)B_*OUT_N) * 2;
    const bool bf16_logits = (ws_size >= need);

    cvt_w1<<<dim3((HIDDEN * K1 + 255) / 256), dim3(256), 0, stream>>>(W1, W1b);
    cvt_w2<<<dim3((OUT_N * HIDDEN / 8 + 255) / 256), dim3(256), 0, stream>>>(W2, W2b);
    build_x<<<dim3(B_), dim3(256), 0, stream>>>(d_onehot, cat_ix, hvb_ix, hvf_ix,
                                                hvb_top, hvf_top, cat_embeds, hvec_embeds, xb);
    // GEMM1: 128x64 tiles -> grid 16*16=256
    gemm_rt<2, 0><<<dim3(256), dim3(256), 0, stream>>>(
        xb, W1b, b1, (void*)hB, K1, K1 / 32, HIDDEN, HIDDEN - 1, 16);
    // GEMM2: 128x128 tiles -> grid 16*79=1264
    if (bf16_logits) {
        gemm_rt<4, 1><<<dim3(16 * 79), dim3(256), 0, stream>>>(
            hB, W2b, b2, (void*)lg, HIDDEN, HIDDEN / 32, OUT_N, OUT_N - 1, 16);
        lsm_b<<<dim3(B_), dim3(256), 0, stream>>>(lg, out);
    } else {
        gemm_rt<4, 2><<<dim3(16 * 79), dim3(256), 0, stream>>>(
            hB, W2b, b2, (void*)out, HIDDEN, HIDDEN / 32, OUT_N, OUT_N - 1, 16);
        lsm_f<<<dim3(B_), dim3(256), 0, stream>>>(out);
    }
}

// Round 4
// 116.293 us; speedup vs baseline: 1.5321x; 1.0252x over previous
//
#include <hip/hip_runtime.h>

#define B_      2048
#define SYN     128
#define SEM     256
#define IN_DIM  647
#define K1      704      // 647 padded to 22*32
#define HIDDEN  1024
#define OUT_N   10000
#define NNZ     8

typedef __bf16 bf16x8 __attribute__((ext_vector_type(8)));
typedef float  f32x4  __attribute__((ext_vector_type(4)));
typedef __attribute__((address_space(3))) const unsigned short* lds_cp;

__device__ __forceinline__ unsigned short f2b(float v) {
    __bf16 b = (__bf16)v;
    return __builtin_bit_cast(unsigned short, b);
}

// --------------------------- fused prep: cvt_w1 + cvt_w2 + build_x ----------
#define NB_W1 2816   // HIDDEN*K1/256
#define NB_W2 5000   // OUT_N*HIDDEN/8/256
__global__ __launch_bounds__(256) void prep(
    const float* __restrict__ W1,  unsigned short* __restrict__ W1b,
    const float* __restrict__ W2,  unsigned short* __restrict__ W2b,
    const float* __restrict__ d_onehot,
    const int*   __restrict__ cat_ix,
    const int*   __restrict__ hvb_ix,
    const int*   __restrict__ hvf_ix,
    const float* __restrict__ hvb_top,
    const float* __restrict__ hvf_top,
    const float* __restrict__ cat_embeds,
    const float* __restrict__ hvec_embeds,
    unsigned short* __restrict__ xb)
{
    const int bb = blockIdx.x, t = threadIdx.x;
    if (bb < NB_W1) {
        int idx = bb * 256 + t;
        int r = idx / K1, c = idx - r * K1;
        W1b[idx] = f2b(c < IN_DIM ? W1[r * IN_DIM + c] : 0.f);
        return;
    }
    if (bb < NB_W1 + NB_W2) {
        size_t i = (size_t)(bb - NB_W1) * 256 + t;   // 8-elem group
        const float4* src = (const float4*)(W2 + i * 8);
        float4 a = src[0], b = src[1];
        ushort u[8] = { f2b(a.x), f2b(a.y), f2b(a.z), f2b(a.w),
                        f2b(b.x), f2b(b.y), f2b(b.z), f2b(b.w) };
        *(uint4*)(W2b + i * 8) = *(const uint4*)u;
        return;
    }
    // ---- build_x: one block per batch row
    const int b = bb - (NB_W1 + NB_W2);
    unsigned short* xrow = xb + (size_t)b * K1;
    if (t < SYN) {
        int c = cat_ix[b];
        xrow[t] = f2b(cat_embeds[(size_t)c * SYN + t]);
    }
    {
        int ix[NNZ];
        #pragma unroll
        for (int j = 0; j < NNZ; ++j) ix[j] = hvb_ix[b * NNZ + j];
        float s = hvb_top[(size_t)b * SEM + t];
        #pragma unroll
        for (int j = 0; j < NNZ; ++j) {
            bool dup = false;
            for (int k2 = 0; k2 < j; ++k2) dup = dup || (ix[j] == ix[k2]);
            if (!dup) s += hvec_embeds[(size_t)ix[j] * SEM + t];
        }
        xrow[SYN + t] = f2b(s);
    }
    {
        int ix[NNZ];
        #pragma unroll
        for (int j = 0; j < NNZ; ++j) ix[j] = hvf_ix[b * NNZ + j];
        float s = hvf_top[(size_t)b * SEM + t];
        #pragma unroll
        for (int j = 0; j < NNZ; ++j) {
            bool dup = false;
            for (int k2 = 0; k2 < j; ++k2) dup = dup || (ix[j] == ix[k2]);
            if (!dup) s += hvec_embeds[(size_t)ix[j] * SEM + t];
        }
        xrow[SYN + SEM + t] = f2b(s);
    }
    if (t < 7)       xrow[640 + t] = f2b(d_onehot[b * 7 + t]);
    else if (t < 64) xrow[640 + t] = 0;
}

// ------------------------------------------------------------- GEMM template ---
// C = A(M,K) @ B(N,K)^T, bf16 in, fp32 acc. BM=128, BN=32*NI, BK=32.
// 4 waves (2Mx2N). Ring-4 LDS, 3-ahead staging, FRAGMENT PIPELINE:
// part p: read tile p+1 frags (no wait) | stage tile p+3 | lgkmcnt(old reads)
//         | MFMA tile p | vmcnt(4) | barrier  (vmcnt->barrier = cross-wave
// residency broadcast: tiles <= p+2 resident for ALL waves after barrier).
// nt must be EVEN (2 parts per loop body for static frag-set swap, rule #20).
// MODE 0: bias+relu -> bf16. MODE 1: bias -> bf16, col guard. MODE 2: fp32.
template<int NI, int MODE>
__global__ __launch_bounds__(256) void gemm_rt(
    const unsigned short* __restrict__ A,
    const unsigned short* __restrict__ Bm,
    const float* __restrict__ bias,
    void* __restrict__ outp,
    int K, int nt, int ncols, int nbm1, int nm)
{
    constexpr int BN    = 32 * NI;
    constexpr int NB_CH = NI / 2;
    __shared__ __align__(16) unsigned short lds_a[4][128 * 32];
    __shared__ __align__(16) unsigned short lds_b[4][BN * 32];

    const int tid = threadIdx.x;
    const int wv = tid >> 6, ln = tid & 63;
    const int wr = wv >> 1, wc = wv & 1;
    const int lr = ln & 15, lh = ln >> 4;

    const int g   = gridDim.x;
    const int nw  = (blockIdx.x & 7) * (g >> 3) + (blockIdx.x >> 3);
    const int mt  = nw % nm, ntile = nw / nm;
    const int m0  = mt * 128, n0 = ntile * BN;

    // staging: pre-swizzled global source, linear LDS dest (rule 21)
    const unsigned short* srcA[2];
    const unsigned short* srcB[NB_CH];
    #pragma unroll
    for (int i = 0; i < 2; ++i) {
        int c = tid + i * 256;
        int row = c >> 2, colL = (((c & 3) ^ ((c >> 3) & 3)) << 3);
        srcA[i] = A + (size_t)(m0 + row) * K + colL;
    }
    #pragma unroll
    for (int j = 0; j < NB_CH; ++j) {
        int c = tid + j * 256;
        int row = c >> 2, colL = (((c & 3) ^ ((c >> 3) & 3)) << 3);
        int gr = n0 + row; if (gr > nbm1) gr = nbm1;
        srcB[j] = Bm + (size_t)gr * K + colL;
    }

    auto stage = [&](int buf, int kt) {
        #pragma unroll
        for (int i = 0; i < 2; ++i)
            __builtin_amdgcn_global_load_lds(
                (__attribute__((address_space(1))) const void*)(srcA[i] + kt),
                (__attribute__((address_space(3))) void*)&lds_a[buf][(tid + i * 256) * 8], 16, 0, 0);
        #pragma unroll
        for (int j = 0; j < NB_CH; ++j)
            __builtin_amdgcn_global_load_lds(
                (__attribute__((address_space(1))) const void*)(srcB[j] + kt),
                (__attribute__((address_space(3))) void*)&lds_b[buf][(tid + j * 256) * 8], 16, 0, 0);
    };

    // swizzled ds_read byte offsets (verified conflict-free R3)
    int a_off[4], b_off[NI];
    #pragma unroll
    for (int mi = 0; mi < 4; ++mi) {
        int row = wr * 64 + mi * 16 + lr;
        a_off[mi] = (row * 64 + lh * 16) ^ (((row >> 1) & 3) << 4);
    }
    #pragma unroll
    for (int ni = 0; ni < NI; ++ni) {
        int row = wc * 16 * NI + ni * 16 + lr;
        b_off[ni] = (row * 64 + lh * 16) ^ (((row >> 1) & 3) << 4);
    }

    f32x4 acc[4][NI];
    {
        f32x4 z = {0.f, 0.f, 0.f, 0.f};
        #pragma unroll
        for (int i = 0; i < 4; ++i)
            #pragma unroll
            for (int j = 0; j < NI; ++j) acc[i][j] = z;
    }

    auto frag_read = [&](bf16x8 (&af)[4], bf16x8 (&bfv)[NI], int buf) {
        lds_cp pa = (lds_cp)&lds_a[buf][0];
        lds_cp pb = (lds_cp)&lds_b[buf][0];
        #pragma unroll
        for (int mi = 0; mi < 4; ++mi) {
            unsigned ad = (unsigned)(unsigned long long)pa + a_off[mi];
            asm volatile("ds_read_b128 %0, %1" : "=v"(af[mi]) : "v"(ad));
        }
        #pragma unroll
        for (int ni = 0; ni < NI; ++ni) {
            unsigned ad = (unsigned)(unsigned long long)pb + b_off[ni];
            asm volatile("ds_read_b128 %0, %1" : "=v"(bfv[ni]) : "v"(ad));
        }
    };
    auto do_mfma = [&](bf16x8 (&af)[4], bf16x8 (&bfv)[NI]) {
        #pragma unroll
        for (int mi = 0; mi < 4; ++mi)
            #pragma unroll
            for (int ni = 0; ni < NI; ++ni)
                acc[mi][ni] = __builtin_amdgcn_mfma_f32_16x16x32_bf16(af[mi], bfv[ni], acc[mi][ni], 0, 0, 0);
    };
    // one pipeline part: read frags(tile p+1), stage(tile p+3), MFMA(tile p)
    auto do_part = [&](bf16x8 (&rA)[4], bf16x8 (&rB)[NI],
                       bf16x8 (&mA)[4], bf16x8 (&mB)[NI], int p) {
        frag_read(rA, rB, (p + 1) & 3);
        int tp = p + 3; if (tp > nt - 1) tp = nt - 1;   // clamped re-stage keeps vmcnt uniform
        stage((p + 3) & 3, tp * 32);
        if constexpr (NI == 4) asm volatile("s_waitcnt lgkmcnt(8)" ::: "memory");
        else                   asm volatile("s_waitcnt lgkmcnt(6)" ::: "memory");
        __builtin_amdgcn_sched_barrier(0);              // rule #18
        __builtin_amdgcn_s_setprio(1);
        do_mfma(mA, mB);
        __builtin_amdgcn_s_setprio(0);
        if constexpr (NI == 4) asm volatile("s_waitcnt vmcnt(4)" ::: "memory");
        else                   asm volatile("s_waitcnt vmcnt(3)" ::: "memory");
        __builtin_amdgcn_s_barrier();                   // residency broadcast
    };

    // prologue: stage tiles 0,1,2; ensure 0,1 resident; read tile-0 frags
    stage(0, 0);
    stage(1, 32);
    stage(2, 64);
    if constexpr (NI == 4) asm volatile("s_waitcnt vmcnt(4)" ::: "memory");
    else                   asm volatile("s_waitcnt vmcnt(3)" ::: "memory");
    __builtin_amdgcn_s_barrier();

    bf16x8 afX[4], bfX[NI], afY[4], bfY[NI];
    frag_read(afX, bfX, 0);

    for (int t = 0; t < nt; t += 2) {
        do_part(afY, bfY, afX, bfX, t);
        do_part(afX, bfX, afY, bfY, t + 1);
    }

    // epilogue: C/D layout col=ln&15, row=(ln>>4)*4+r
    #pragma unroll
    for (int mi = 0; mi < 4; ++mi) {
        int row = m0 + wr * 64 + mi * 16 + lh * 4;
        #pragma unroll
        for (int ni = 0; ni < NI; ++ni) {
            int col = n0 + wc * 16 * NI + ni * 16 + lr;
            if (col < ncols) {
                float bb = bias[col];
                if (MODE == 0) {
                    unsigned short* H = (unsigned short*)outp;
                    #pragma unroll
                    for (int r = 0; r < 4; ++r)
                        H[(size_t)(row + r) * ncols + col] = f2b(fmaxf(acc[mi][ni][r] + bb, 0.f));
                } else if (MODE == 1) {
                    unsigned short* H = (unsigned short*)outp;
                    #pragma unroll
                    for (int r = 0; r < 4; ++r)
                        H[(size_t)(row + r) * ncols + col] = f2b(acc[mi][ni][r] + bb);
                } else {
                    float* O = (float*)outp;
                    #pragma unroll
                    for (int r = 0; r < 4; ++r)
                        O[(size_t)(row + r) * ncols + col] = acc[mi][ni][r] + bb;
                }
            }
        }
    }
}

// --------------------------------------------- logsoftmax, bf16-logit input ---
__global__ __launch_bounds__(256) void lsm_b(const unsigned short* __restrict__ lg,
                                             float* __restrict__ out) {
    __shared__ __align__(16) float rowbuf[OUT_N];
    __shared__ float red[8];
    const int t = threadIdx.x, wv = t >> 6, ln = t & 63;
    const unsigned short* l = lg + (size_t)blockIdx.x * OUT_N;
    float* o = out + (size_t)blockIdx.x * OUT_N;

    float mx = -3.4e38f;
    for (int i = t; i < OUT_N / 8; i += 256) {
        uint4 v = ((const uint4*)l)[i];
        float f[8];
        unsigned w[4] = {v.x, v.y, v.z, v.w};
        #pragma unroll
        for (int j = 0; j < 4; ++j) {
            f[2*j]   = __builtin_bit_cast(float, w[j] << 16);
            f[2*j+1] = __builtin_bit_cast(float, w[j] & 0xffff0000u);
        }
        #pragma unroll
        for (int j = 0; j < 8; ++j) {
            rowbuf[i * 8 + j] = f[j];
            mx = fmaxf(mx, f[j]);
        }
    }
    #pragma unroll
    for (int off = 32; off > 0; off >>= 1) mx = fmaxf(mx, __shfl_xor(mx, off, 64));
    if (ln == 0) red[wv] = mx;
    __syncthreads();
    float m4 = fmaxf(fmaxf(red[0], red[1]), fmaxf(red[2], red[3]));

    float s = 0.f;
    for (int i = t; i < OUT_N; i += 256) s += __expf(rowbuf[i] - m4);
    #pragma unroll
    for (int off = 32; off > 0; off >>= 1) s += __shfl_xor(s, off, 64);
    if (ln == 0) red[4 + wv] = s;
    __syncthreads();
    float lz = m4 + logf(red[4] + red[5] + red[6] + red[7]);

    for (int i = t; i < OUT_N / 4; i += 256) {
        float4 v = { rowbuf[i*4] - lz, rowbuf[i*4+1] - lz,
                     rowbuf[i*4+2] - lz, rowbuf[i*4+3] - lz };
        ((float4*)o)[i] = v;
    }
}

// --------------------------------------------- logsoftmax, fp32 in-place ---
__global__ __launch_bounds__(256) void lsm_f(float* __restrict__ out) {
    __shared__ __align__(16) float rowbuf[OUT_N];
    __shared__ float red[8];
    const int t = threadIdx.x, wv = t >> 6, ln = t & 63;
    float* o = out + (size_t)blockIdx.x * OUT_N;

    float mx = -3.4e38f;
    for (int i = t; i < OUT_N / 4; i += 256) {
        float4 v = ((const float4*)o)[i];
        rowbuf[i*4] = v.x; rowbuf[i*4+1] = v.y; rowbuf[i*4+2] = v.z; rowbuf[i*4+3] = v.w;
        mx = fmaxf(fmaxf(mx, fmaxf(v.x, v.y)), fmaxf(v.z, v.w));
    }
    #pragma unroll
    for (int off = 32; off > 0; off >>= 1) mx = fmaxf(mx, __shfl_xor(mx, off, 64));
    if (ln == 0) red[wv] = mx;
    __syncthreads();
    float m4 = fmaxf(fmaxf(red[0], red[1]), fmaxf(red[2], red[3]));

    float s = 0.f;
    for (int i = t; i < OUT_N; i += 256) s += __expf(rowbuf[i] - m4);
    #pragma unroll
    for (int off = 32; off > 0; off >>= 1) s += __shfl_xor(s, off, 64);
    if (ln == 0) red[4 + wv] = s;
    __syncthreads();
    float lz = m4 + logf(red[4] + red[5] + red[6] + red[7]);

    for (int i = t; i < OUT_N / 4; i += 256) {
        float4 v = { rowbuf[i*4] - lz, rowbuf[i*4+1] - lz,
                     rowbuf[i*4+2] - lz, rowbuf[i*4+3] - lz };
        ((float4*)o)[i] = v;
    }
}

// ----------------------------------------------------------------- launch ---
extern "C" void kernel_launch(void* const* d_in, const int* in_sizes, int n_in,
                              void* d_out, int out_size, void* d_ws, size_t ws_size,
                              hipStream_t stream) {
    const float* d_onehot    = (const float*)d_in[0];
    const int*   cat_ix      = (const int*)  d_in[1];
    const int*   hvb_ix      = (const int*)  d_in[2];
    const int*   hvf_ix      = (const int*)  d_in[3];
    const float* hvb_top     = (const float*)d_in[4];
    const float* hvf_top     = (const float*)d_in[5];
    const float* cat_embeds  = (const float*)d_in[6];
    const float* hvec_embeds = (const float*)d_in[7];
    const float* W1          = (const float*)d_in[8];
    const float* b1          = (const float*)d_in[9];
    const float* W2          = (const float*)d_in[10];
    const float* b2          = (const float*)d_in[11];
    float* out = (float*)d_out;

    unsigned short* xb  = (unsigned short*)d_ws;               // 2048 x 704
    unsigned short* W1b = xb  + (size_t)B_ * K1;               // 1024 x 704
    unsigned short* hB  = W1b + (size_t)HIDDEN * K1;           // 2048 x 1024
    unsigned short* W2b = hB  + (size_t)B_ * HIDDEN;           // 10000 x 1024
    unsigned short* lg  = W2b + (size_t)OUT_N * HIDDEN;        // 2048 x 10000 bf16 logits
    const size_t need = ((size_t)B_*K1 + (size_t)HIDDEN*K1 + (size_t)B_*HIDDEN
                         + (size_t)OUT_N*HIDDEN + (size_t)B_*OUT_N) * 2;
    const bool bf16_logits = (ws_size >= need);

    prep<<<dim3(NB_W1 + NB_W2 + B_), dim3(256), 0, stream>>>(
        W1, W1b, W2, W2b, d_onehot, cat_ix, hvb_ix, hvf_ix,
        hvb_top, hvf_top, cat_embeds, hvec_embeds, xb);
    // GEMM1: 128x64 tiles -> grid 16*16=256, nt=22 (even)
    gemm_rt<2, 0><<<dim3(256), dim3(256), 0, stream>>>(
        xb, W1b, b1, (void*)hB, K1, K1 / 32, HIDDEN, HIDDEN - 1, 16);
    // GEMM2: 128x128 tiles -> grid 16*79=1264, nt=32 (even)
    if (bf16_logits) {
        gemm_rt<4, 1><<<dim3(16 * 79), dim3(256), 0, stream>>>(
            hB, W2b, b2, (void*)lg, HIDDEN, HIDDEN / 32, OUT_N, OUT_N - 1, 16);
        lsm_b<<<dim3(B_), dim3(256), 0, stream>>>(lg, out);
    } else {
        gemm_rt<4, 2><<<dim3(16 * 79), dim3(256), 0, stream>>>(
            hB, W2b, b2, (void*)out, HIDDEN, HIDDEN / 32, OUT_N, OUT_N - 1, 16);
        lsm_f<<<dim3(B_), dim3(256), 0, stream>>>(out);
    }
}

// Round 5
// 102.937 us; speedup vs baseline: 1.7309x; 1.1297x over previous
//
#include <hip/hip_runtime.h>

#define B_      2048
#define SYN     128
#define SEM     256
#define IN_DIM  647
#define K1      704      // 647 padded to 22*32
#define HIDDEN  1024
#define OUT_N   10000
#define NNZ     8

typedef __bf16 bf16x8 __attribute__((ext_vector_type(8)));
typedef float  f32x4  __attribute__((ext_vector_type(4)));
typedef __attribute__((address_space(3))) const unsigned short* lds_cp;

__device__ __forceinline__ unsigned short f2b(float v) {
    __bf16 b = (__bf16)v;
    return __builtin_bit_cast(unsigned short, b);
}

// --------------------------- fused prep: cvt_w1 + cvt_w2 + build_x ----------
#define NB_W1 2816   // HIDDEN*K1/256
#define NB_W2 5000   // OUT_N*HIDDEN/8/256
__global__ __launch_bounds__(256) void prep(
    const float* __restrict__ W1,  unsigned short* __restrict__ W1b,
    const float* __restrict__ W2,  unsigned short* __restrict__ W2b,
    const float* __restrict__ d_onehot,
    const int*   __restrict__ cat_ix,
    const int*   __restrict__ hvb_ix,
    const int*   __restrict__ hvf_ix,
    const float* __restrict__ hvb_top,
    const float* __restrict__ hvf_top,
    const float* __restrict__ cat_embeds,
    const float* __restrict__ hvec_embeds,
    unsigned short* __restrict__ xb)
{
    const int bb = blockIdx.x, t = threadIdx.x;
    if (bb < NB_W1) {
        int idx = bb * 256 + t;
        int r = idx / K1, c = idx - r * K1;
        W1b[idx] = f2b(c < IN_DIM ? W1[r * IN_DIM + c] : 0.f);
        return;
    }
    if (bb < NB_W1 + NB_W2) {
        size_t i = (size_t)(bb - NB_W1) * 256 + t;   // 8-elem group
        const float4* src = (const float4*)(W2 + i * 8);
        float4 a = src[0], b = src[1];
        ushort u[8] = { f2b(a.x), f2b(a.y), f2b(a.z), f2b(a.w),
                        f2b(b.x), f2b(b.y), f2b(b.z), f2b(b.w) };
        *(uint4*)(W2b + i * 8) = *(const uint4*)u;
        return;
    }
    const int b = bb - (NB_W1 + NB_W2);
    unsigned short* xrow = xb + (size_t)b * K1;
    if (t < SYN) {
        int c = cat_ix[b];
        xrow[t] = f2b(cat_embeds[(size_t)c * SYN + t]);
    }
    {
        int ix[NNZ];
        #pragma unroll
        for (int j = 0; j < NNZ; ++j) ix[j] = hvb_ix[b * NNZ + j];
        float s = hvb_top[(size_t)b * SEM + t];
        #pragma unroll
        for (int j = 0; j < NNZ; ++j) {
            bool dup = false;
            for (int k2 = 0; k2 < j; ++k2) dup = dup || (ix[j] == ix[k2]);
            if (!dup) s += hvec_embeds[(size_t)ix[j] * SEM + t];
        }
        xrow[SYN + t] = f2b(s);
    }
    {
        int ix[NNZ];
        #pragma unroll
        for (int j = 0; j < NNZ; ++j) ix[j] = hvf_ix[b * NNZ + j];
        float s = hvf_top[(size_t)b * SEM + t];
        #pragma unroll
        for (int j = 0; j < NNZ; ++j) {
            bool dup = false;
            for (int k2 = 0; k2 < j; ++k2) dup = dup || (ix[j] == ix[k2]);
            if (!dup) s += hvec_embeds[(size_t)ix[j] * SEM + t];
        }
        xrow[SYN + SEM + t] = f2b(s);
    }
    if (t < 7)       xrow[640 + t] = f2b(d_onehot[b * 7 + t]);
    else if (t < 64) xrow[640 + t] = 0;
}

// ----------------------- GEMM1 / fallback template (R3/R4 proven) -----------
template<int NI, int MODE>
__global__ __launch_bounds__(256) void gemm_rt(
    const unsigned short* __restrict__ A,
    const unsigned short* __restrict__ Bm,
    const float* __restrict__ bias,
    void* __restrict__ outp,
    int K, int nt, int ncols, int nbm1, int nm)
{
    constexpr int BN    = 32 * NI;
    constexpr int NB_CH = NI / 2;
    __shared__ __align__(16) unsigned short lds_a[4][128 * 32];
    __shared__ __align__(16) unsigned short lds_b[4][BN * 32];

    const int tid = threadIdx.x;
    const int wv = tid >> 6, ln = tid & 63;
    const int wr = wv >> 1, wc = wv & 1;
    const int lr = ln & 15, lh = ln >> 4;

    const int g   = gridDim.x;
    const int nw  = (blockIdx.x & 7) * (g >> 3) + (blockIdx.x >> 3);
    const int mt  = nw % nm, ntile = nw / nm;
    const int m0  = mt * 128, n0 = ntile * BN;

    const unsigned short* srcA[2];
    const unsigned short* srcB[NB_CH];
    #pragma unroll
    for (int i = 0; i < 2; ++i) {
        int c = tid + i * 256;
        int row = c >> 2, colL = (((c & 3) ^ ((c >> 3) & 3)) << 3);
        srcA[i] = A + (size_t)(m0 + row) * K + colL;
    }
    #pragma unroll
    for (int j = 0; j < NB_CH; ++j) {
        int c = tid + j * 256;
        int row = c >> 2, colL = (((c & 3) ^ ((c >> 3) & 3)) << 3);
        int gr = n0 + row; if (gr > nbm1) gr = nbm1;
        srcB[j] = Bm + (size_t)gr * K + colL;
    }

    auto stage = [&](int buf, int kt) {
        #pragma unroll
        for (int i = 0; i < 2; ++i)
            __builtin_amdgcn_global_load_lds(
                (__attribute__((address_space(1))) const void*)(srcA[i] + kt),
                (__attribute__((address_space(3))) void*)&lds_a[buf][(tid + i * 256) * 8], 16, 0, 0);
        #pragma unroll
        for (int j = 0; j < NB_CH; ++j)
            __builtin_amdgcn_global_load_lds(
                (__attribute__((address_space(1))) const void*)(srcB[j] + kt),
                (__attribute__((address_space(3))) void*)&lds_b[buf][(tid + j * 256) * 8], 16, 0, 0);
    };

    int a_off[4], b_off[NI];
    #pragma unroll
    for (int mi = 0; mi < 4; ++mi) {
        int row = wr * 64 + mi * 16 + lr;
        a_off[mi] = (row * 64 + lh * 16) ^ (((row >> 1) & 3) << 4);
    }
    #pragma unroll
    for (int ni = 0; ni < NI; ++ni) {
        int row = wc * 16 * NI + ni * 16 + lr;
        b_off[ni] = (row * 64 + lh * 16) ^ (((row >> 1) & 3) << 4);
    }

    f32x4 acc[4][NI];
    {
        f32x4 z = {0.f, 0.f, 0.f, 0.f};
        #pragma unroll
        for (int i = 0; i < 4; ++i)
            #pragma unroll
            for (int j = 0; j < NI; ++j) acc[i][j] = z;
    }

    auto frag_read = [&](bf16x8 (&af)[4], bf16x8 (&bfv)[NI], int buf) {
        lds_cp pa = (lds_cp)&lds_a[buf][0];
        lds_cp pb = (lds_cp)&lds_b[buf][0];
        #pragma unroll
        for (int mi = 0; mi < 4; ++mi) {
            unsigned ad = (unsigned)(unsigned long long)pa + a_off[mi];
            asm volatile("ds_read_b128 %0, %1" : "=v"(af[mi]) : "v"(ad));
        }
        #pragma unroll
        for (int ni = 0; ni < NI; ++ni) {
            unsigned ad = (unsigned)(unsigned long long)pb + b_off[ni];
            asm volatile("ds_read_b128 %0, %1" : "=v"(bfv[ni]) : "v"(ad));
        }
    };
    auto do_mfma = [&](bf16x8 (&af)[4], bf16x8 (&bfv)[NI]) {
        #pragma unroll
        for (int mi = 0; mi < 4; ++mi)
            #pragma unroll
            for (int ni = 0; ni < NI; ++ni)
                acc[mi][ni] = __builtin_amdgcn_mfma_f32_16x16x32_bf16(af[mi], bfv[ni], acc[mi][ni], 0, 0, 0);
    };
    auto do_part = [&](bf16x8 (&rA)[4], bf16x8 (&rB)[NI],
                       bf16x8 (&mA)[4], bf16x8 (&mB)[NI], int p) {
        frag_read(rA, rB, (p + 1) & 3);
        int tp = p + 3; if (tp > nt - 1) tp = nt - 1;
        stage((p + 3) & 3, tp * 32);
        if constexpr (NI == 4) asm volatile("s_waitcnt lgkmcnt(8)" ::: "memory");
        else                   asm volatile("s_waitcnt lgkmcnt(6)" ::: "memory");
        __builtin_amdgcn_sched_barrier(0);
        __builtin_amdgcn_s_setprio(1);
        do_mfma(mA, mB);
        __builtin_amdgcn_s_setprio(0);
        if constexpr (NI == 4) asm volatile("s_waitcnt vmcnt(4)" ::: "memory");
        else                   asm volatile("s_waitcnt vmcnt(3)" ::: "memory");
        __builtin_amdgcn_s_barrier();
    };

    stage(0, 0);
    stage(1, 32);
    stage(2, 64);
    if constexpr (NI == 4) asm volatile("s_waitcnt vmcnt(4)" ::: "memory");
    else                   asm volatile("s_waitcnt vmcnt(3)" ::: "memory");
    __builtin_amdgcn_s_barrier();

    bf16x8 afX[4], bfX[NI], afY[4], bfY[NI];
    frag_read(afX, bfX, 0);

    for (int t = 0; t < nt; t += 2) {
        do_part(afY, bfY, afX, bfX, t);
        do_part(afX, bfX, afY, bfY, t + 1);
    }

    #pragma unroll
    for (int mi = 0; mi < 4; ++mi) {
        int row = m0 + wr * 64 + mi * 16 + lh * 4;
        #pragma unroll
        for (int ni = 0; ni < NI; ++ni) {
            int col = n0 + wc * 16 * NI + ni * 16 + lr;
            if (col < ncols) {
                float bb = bias[col];
                if (MODE == 0) {
                    unsigned short* H = (unsigned short*)outp;
                    #pragma unroll
                    for (int r = 0; r < 4; ++r)
                        H[(size_t)(row + r) * ncols + col] = f2b(fmaxf(acc[mi][ni][r] + bb, 0.f));
                } else {
                    float* O = (float*)outp;
                    #pragma unroll
                    for (int r = 0; r < 4; ++r)
                        O[(size_t)(row + r) * ncols + col] = acc[mi][ni][r] + bb;
                }
            }
        }
    }
}

// ---------------- GEMM2: 256x320 tile, 8 waves, BK=32, ring-4, 2-phase ------
// One block per CU (grid 256 = 8 m-tiles x 32 n-tiles, perfect pack).
// Wave tile 128x80 (2M x 4N waves). Per K-tile: ph0 {read B(5)+A(4), stage A(t+3),
// bar, lgkm0, 20 MFMA mi0-3, bar}; ph1 {read A(4), stage B(t+3), bar, lgkm0,
// 20 MFMA mi4-7, vmcnt(10), bar}.
// Residency proof: 5 stage-instrs/tile (2A+3B). vmcnt(10) at end of tile t
// leaves exactly tiles {t,t-1}'s stages outstanding => all stages through
// tile t-2 (targeting tile t+1) complete => tile t+1 resident. Ring-4:
// stage at tile t writes slot (t+3)&3 = slot of tile t-1, whose last reads
// completed (lgkm0) before the end-of-(t-1) barrier, which precedes any
// tile-t stage issue. Clamped tail re-stages tile 31 with identical data.
__global__ __launch_bounds__(512, 2) void gemm2_320(
    const unsigned short* __restrict__ A,    // hB: 2048 x 1024
    const unsigned short* __restrict__ Bm,   // W2b: 10000 x 1024
    const float* __restrict__ bias,
    unsigned short* __restrict__ H)          // bf16 logits 2048 x 10000
{
    __shared__ __align__(16) unsigned short lA[4][8192];    // 4 x 16KB
    __shared__ __align__(16) unsigned short lB[4][10240];   // 4 x 20KB
    const int tid = threadIdx.x;
    const int wv = tid >> 6, ln = tid & 63;
    const int wr = wv >> 2, wc = wv & 3;        // 2M x 4N
    const int lr = ln & 15, lh = ln >> 4;

    // XCD map: 256 blocks; XCD x gets n-panels 4x..4x+3 (2.5MB, L2-fits) x all 8 m
    const int nw = (blockIdx.x & 7) * 32 + (blockIdx.x >> 3);
    const int m0 = (nw & 7) * 256;
    const int n0 = (nw >> 3) * 320;

    // staging sources (pre-swizzled global cols; linear LDS dest)
    const unsigned short* srcA[2];
    const unsigned short* srcB[2];
    const unsigned short* srcB2;
    #pragma unroll
    for (int j = 0; j < 2; ++j) {
        int c = j * 512 + tid;
        int row = c >> 2, colL = (((c & 3) ^ ((c >> 3) & 3)) << 3);
        srcA[j] = A + (size_t)(m0 + row) * HIDDEN + colL;
        int gr = n0 + row; if (gr > OUT_N - 1) gr = OUT_N - 1;
        srcB[j] = Bm + (size_t)gr * HIDDEN + colL;
    }
    const int c2 = 1024 + (wv & 3) * 64 + ln;   // waves 4-7 duplicate 0-3 (benign)
    {
        int row = c2 >> 2, colL = (((c2 & 3) ^ ((c2 >> 3) & 3)) << 3);
        int gr = n0 + row; if (gr > OUT_N - 1) gr = OUT_N - 1;
        srcB2 = Bm + (size_t)gr * HIDDEN + colL;
    }

    auto stageA = [&](int slot, int kt) {
        #pragma unroll
        for (int j = 0; j < 2; ++j)
            __builtin_amdgcn_global_load_lds(
                (__attribute__((address_space(1))) const void*)(srcA[j] + kt),
                (__attribute__((address_space(3))) void*)&lA[slot][(j * 512 + tid) * 8], 16, 0, 0);
    };
    auto stageB = [&](int slot, int kt) {
        #pragma unroll
        for (int j = 0; j < 2; ++j)
            __builtin_amdgcn_global_load_lds(
                (__attribute__((address_space(1))) const void*)(srcB[j] + kt),
                (__attribute__((address_space(3))) void*)&lB[slot][(j * 512 + tid) * 8], 16, 0, 0);
        __builtin_amdgcn_global_load_lds(
            (__attribute__((address_space(1))) const void*)(srcB2 + kt),
            (__attribute__((address_space(3))) void*)&lB[slot][c2 * 8], 16, 0, 0);
    };

    // swizzled ds_read byte offsets (R3-verified: 0 bank conflicts)
    int a_off[8], b_off[5];
    #pragma unroll
    for (int mi = 0; mi < 8; ++mi) {
        int row = wr * 128 + mi * 16 + lr;
        a_off[mi] = (row * 64 + lh * 16) ^ (((row >> 1) & 3) << 4);
    }
    #pragma unroll
    for (int ni = 0; ni < 5; ++ni) {
        int row = wc * 80 + ni * 16 + lr;
        b_off[ni] = (row * 64 + lh * 16) ^ (((row >> 1) & 3) << 4);
    }

    f32x4 acc[8][5];
    {
        f32x4 z = {0.f, 0.f, 0.f, 0.f};
        #pragma unroll
        for (int i = 0; i < 8; ++i)
            #pragma unroll
            for (int j = 0; j < 5; ++j) acc[i][j] = z;
    }

    // prologue: tiles 0,1,2 (15 instrs); vmcnt(10) -> tile 0 resident
    stageA(0, 0);  stageB(0, 0);
    stageA(1, 32); stageB(1, 32);
    stageA(2, 64); stageB(2, 64);
    asm volatile("s_waitcnt vmcnt(10)" ::: "memory");
    __builtin_amdgcn_s_barrier();

    for (int t = 0; t < 32; ++t) {
        const int slot = t & 3;
        int tp = t + 3; if (tp > 31) tp = 31;
        const int pslot = tp & 3;
        lds_cp pA = (lds_cp)&lA[slot][0];
        lds_cp pB = (lds_cp)&lB[slot][0];
        bf16x8 af[4], bfv[5];

        // ---- phase 0
        #pragma unroll
        for (int ni = 0; ni < 5; ++ni) {
            unsigned ad = (unsigned)(unsigned long long)pB + b_off[ni];
            asm volatile("ds_read_b128 %0, %1" : "=v"(bfv[ni]) : "v"(ad));
        }
        #pragma unroll
        for (int mi = 0; mi < 4; ++mi) {
            unsigned ad = (unsigned)(unsigned long long)pA + a_off[mi];
            asm volatile("ds_read_b128 %0, %1" : "=v"(af[mi]) : "v"(ad));
        }
        stageA(pslot, tp * 32);
        __builtin_amdgcn_s_barrier();
        asm volatile("s_waitcnt lgkmcnt(0)" ::: "memory");
        __builtin_amdgcn_sched_barrier(0);
        __builtin_amdgcn_s_setprio(1);
        #pragma unroll
        for (int mi = 0; mi < 4; ++mi)
            #pragma unroll
            for (int ni = 0; ni < 5; ++ni)
                acc[mi][ni] = __builtin_amdgcn_mfma_f32_16x16x32_bf16(af[mi], bfv[ni], acc[mi][ni], 0, 0, 0);
        __builtin_amdgcn_s_setprio(0);
        __builtin_amdgcn_s_barrier();

        // ---- phase 1
        #pragma unroll
        for (int mi = 0; mi < 4; ++mi) {
            unsigned ad = (unsigned)(unsigned long long)pA + a_off[4 + mi];
            asm volatile("ds_read_b128 %0, %1" : "=v"(af[mi]) : "v"(ad));
        }
        stageB(pslot, tp * 32);
        __builtin_amdgcn_s_barrier();
        asm volatile("s_waitcnt lgkmcnt(0)" ::: "memory");
        __builtin_amdgcn_sched_barrier(0);
        __builtin_amdgcn_s_setprio(1);
        #pragma unroll
        for (int mi = 0; mi < 4; ++mi)
            #pragma unroll
            for (int ni = 0; ni < 5; ++ni)
                acc[4 + mi][ni] = __builtin_amdgcn_mfma_f32_16x16x32_bf16(af[mi], bfv[ni], acc[4 + mi][ni], 0, 0, 0);
        __builtin_amdgcn_s_setprio(0);
        asm volatile("s_waitcnt vmcnt(10)" ::: "memory");
        __builtin_amdgcn_s_barrier();
    }

    // epilogue: bias + bf16 store, col-guarded
    #pragma unroll
    for (int mi = 0; mi < 8; ++mi) {
        int row = m0 + wr * 128 + mi * 16 + lh * 4;
        #pragma unroll
        for (int ni = 0; ni < 5; ++ni) {
            int col = n0 + wc * 80 + ni * 16 + lr;
            if (col < OUT_N) {
                float bb = bias[col];
                #pragma unroll
                for (int r = 0; r < 4; ++r)
                    H[(size_t)(row + r) * OUT_N + col] = f2b(acc[mi][ni][r] + bb);
            }
        }
    }
}

// --------------------------------------------- logsoftmax, bf16-logit input ---
__global__ __launch_bounds__(256) void lsm_b(const unsigned short* __restrict__ lg,
                                             float* __restrict__ out) {
    __shared__ __align__(16) float rowbuf[OUT_N];
    __shared__ float red[8];
    const int t = threadIdx.x, wv = t >> 6, ln = t & 63;
    const unsigned short* l = lg + (size_t)blockIdx.x * OUT_N;
    float* o = out + (size_t)blockIdx.x * OUT_N;

    float mx = -3.4e38f;
    for (int i = t; i < OUT_N / 8; i += 256) {
        uint4 v = ((const uint4*)l)[i];
        float f[8];
        unsigned w[4] = {v.x, v.y, v.z, v.w};
        #pragma unroll
        for (int j = 0; j < 4; ++j) {
            f[2*j]   = __builtin_bit_cast(float, w[j] << 16);
            f[2*j+1] = __builtin_bit_cast(float, w[j] & 0xffff0000u);
        }
        #pragma unroll
        for (int j = 0; j < 8; ++j) {
            rowbuf[i * 8 + j] = f[j];
            mx = fmaxf(mx, f[j]);
        }
    }
    #pragma unroll
    for (int off = 32; off > 0; off >>= 1) mx = fmaxf(mx, __shfl_xor(mx, off, 64));
    if (ln == 0) red[wv] = mx;
    __syncthreads();
    float m4 = fmaxf(fmaxf(red[0], red[1]), fmaxf(red[2], red[3]));

    float s = 0.f;
    for (int i = t; i < OUT_N; i += 256) s += __expf(rowbuf[i] - m4);
    #pragma unroll
    for (int off = 32; off > 0; off >>= 1) s += __shfl_xor(s, off, 64);
    if (ln == 0) red[4 + wv] = s;
    __syncthreads();
    float lz = m4 + logf(red[4] + red[5] + red[6] + red[7]);

    for (int i = t; i < OUT_N / 4; i += 256) {
        float4 v = { rowbuf[i*4] - lz, rowbuf[i*4+1] - lz,
                     rowbuf[i*4+2] - lz, rowbuf[i*4+3] - lz };
        ((float4*)o)[i] = v;
    }
}

// --------------------------------------------- logsoftmax, fp32 in-place ---
__global__ __launch_bounds__(256) void lsm_f(float* __restrict__ out) {
    __shared__ __align__(16) float rowbuf[OUT_N];
    __shared__ float red[8];
    const int t = threadIdx.x, wv = t >> 6, ln = t & 63;
    float* o = out + (size_t)blockIdx.x * OUT_N;

    float mx = -3.4e38f;
    for (int i = t; i < OUT_N / 4; i += 256) {
        float4 v = ((const float4*)o)[i];
        rowbuf[i*4] = v.x; rowbuf[i*4+1] = v.y; rowbuf[i*4+2] = v.z; rowbuf[i*4+3] = v.w;
        mx = fmaxf(fmaxf(mx, fmaxf(v.x, v.y)), fmaxf(v.z, v.w));
    }
    #pragma unroll
    for (int off = 32; off > 0; off >>= 1) mx = fmaxf(mx, __shfl_xor(mx, off, 64));
    if (ln == 0) red[wv] = mx;
    __syncthreads();
    float m4 = fmaxf(fmaxf(red[0], red[1]), fmaxf(red[2], red[3]));

    float s = 0.f;
    for (int i = t; i < OUT_N; i += 256) s += __expf(rowbuf[i] - m4);
    #pragma unroll
    for (int off = 32; off > 0; off >>= 1) s += __shfl_xor(s, off, 64);
    if (ln == 0) red[4 + wv] = s;
    __syncthreads();
    float lz = m4 + logf(red[4] + red[5] + red[6] + red[7]);

    for (int i = t; i < OUT_N / 4; i += 256) {
        float4 v = { rowbuf[i*4] - lz, rowbuf[i*4+1] - lz,
                     rowbuf[i*4+2] - lz, rowbuf[i*4+3] - lz };
        ((float4*)o)[i] = v;
    }
}

// ----------------------------------------------------------------- launch ---
extern "C" void kernel_launch(void* const* d_in, const int* in_sizes, int n_in,
                              void* d_out, int out_size, void* d_ws, size_t ws_size,
                              hipStream_t stream) {
    const float* d_onehot    = (const float*)d_in[0];
    const int*   cat_ix      = (const int*)  d_in[1];
    const int*   hvb_ix      = (const int*)  d_in[2];
    const int*   hvf_ix      = (const int*)  d_in[3];
    const float* hvb_top     = (const float*)d_in[4];
    const float* hvf_top     = (const float*)d_in[5];
    const float* cat_embeds  = (const float*)d_in[6];
    const float* hvec_embeds = (const float*)d_in[7];
    const float* W1          = (const float*)d_in[8];
    const float* b1          = (const float*)d_in[9];
    const float* W2          = (const float*)d_in[10];
    const float* b2          = (const float*)d_in[11];
    float* out = (float*)d_out;

    unsigned short* xb  = (unsigned short*)d_ws;               // 2048 x 704
    unsigned short* W1b = xb  + (size_t)B_ * K1;               // 1024 x 704
    unsigned short* hB  = W1b + (size_t)HIDDEN * K1;           // 2048 x 1024
    unsigned short* W2b = hB  + (size_t)B_ * HIDDEN;           // 10000 x 1024
    unsigned short* lg  = W2b + (size_t)OUT_N * HIDDEN;        // 2048 x 10000 bf16 logits
    const size_t need = ((size_t)B_*K1 + (size_t)HIDDEN*K1 + (size_t)B_*HIDDEN
                         + (size_t)OUT_N*HIDDEN + (size_t)B_*OUT_N) * 2;
    const bool bf16_logits = (ws_size >= need);

    prep<<<dim3(NB_W1 + NB_W2 + B_), dim3(256), 0, stream>>>(
        W1, W1b, W2, W2b, d_onehot, cat_ix, hvb_ix, hvf_ix,
        hvb_top, hvf_top, cat_embeds, hvec_embeds, xb);
    // GEMM1: 128x64 tiles -> grid 256, nt=22
    gemm_rt<2, 0><<<dim3(256), dim3(256), 0, stream>>>(
        xb, W1b, b1, (void*)hB, K1, K1 / 32, HIDDEN, HIDDEN - 1, 16);
    if (bf16_logits) {
        gemm2_320<<<dim3(256), dim3(512), 0, stream>>>(hB, W2b, b2, lg);
        lsm_b<<<dim3(B_), dim3(256), 0, stream>>>(lg, out);
    } else {
        gemm_rt<4, 2><<<dim3(16 * 79), dim3(256), 0, stream>>>(
            hB, W2b, b2, (void*)out, HIDDEN, HIDDEN / 32, OUT_N, OUT_N - 1, 16);
        lsm_f<<<dim3(B_), dim3(256), 0, stream>>>(out);
    }
}